// Round 12
// baseline (231.453 us; speedup 1.0000x reference)
//
#include <hip/hip_runtime.h>
#include <hip/hip_bf16.h>
#include <stdint.h>

// B=2, S=2048, D=1024, H=16, HD=64. Inputs fp32, d_out fp32 (resolved r1-r3).
// canon fp32->bf16 -> QKV GEMM (+ fused mask-prep planes: mask*log2e -> bf16
// PRE-PERMUTED into MFMA-fragment order, stashed in d_out) -> flash attn
// (32x32 MFMA, kv-split 2-way, no-max exp2 softmax, mask read straight to
// registers) -> out-proj GEMM fp32.
// r13: XCD decode + mask bf16 in d_out (89->69us). r14: permlane32_swap
// P-exchange + b-partitioned XCD decode (69->59us). r16: mask prep fused into
// QKV launch. r17 probe: QKV ~42us; ~95us of wall is harness reset
// dispatches. r18/r19: fragment-order mask (attn neutral; prep now
// gather-read/coalesced-write; gemm back to (256,2)).
// r20: T4 counted-vmcnt GEMM pipeline — 4-deep LDS buffers, raw s_barrier,
// vmcnt NEVER 0 in the main loop (vmcnt(8) waits only the oldest tile's
// loads, issued 3 compute phases earlier). Same mechanism as the attn loop
// (r8-verified), generalized to counted N. Epilogue drains 8->4->0
// (MODE1 3 loads/stage: 6->3->0). LDS 64KB (MODE0) -> 2 blocks/CU; deep
// pipeline replaces the lost occupancy (AITER model).
#define Bb 2
#define Ss 2048
#define Dd 1024
#define Hh 16
#define HD 64

typedef __attribute__((ext_vector_type(8))) __bf16 bf16x8;
typedef __attribute__((ext_vector_type(4))) __bf16 bf16x4;
typedef __attribute__((ext_vector_type(2))) __bf16 bf16x2;
typedef __attribute__((ext_vector_type(4))) float f32x4;
typedef __attribute__((ext_vector_type(16))) float f32x16;

#define LOG2E 1.44269504088896f
#define SCL2 (0.125f * LOG2E)

// ---- workspace layout (bf16 elements) --------------------------------------
#define HS_N   (Bb * Ss * Dd)
#define W_N    (Dd * Dd)
#define B_N    (Dd)
#define MS_N   ((long)Bb * Ss * Ss)
#define CAN_HS 0
#define CAN_WQ (CAN_HS + HS_N)
#define CAN_BQ (CAN_WQ + W_N)
#define CAN_WK (CAN_BQ + B_N)
#define CAN_BK (CAN_WK + W_N)
#define CAN_WV (CAN_BK + B_N)
#define CAN_BV (CAN_WV + W_N)
#define CAN_WO (CAN_BV + B_N)
#define CAN_BO (CAN_WO + W_N)
#define CAN_END (CAN_BO + B_N)
#define TSZ    (Bb * Hh * Ss * HD)
#define WS_ELEMS (CAN_END + 4 * TSZ)
#define WS_NEED ((size_t)WS_ELEMS * 2)

__device__ __forceinline__ void gl_lds16(const __bf16* g, __bf16* l) {
  __builtin_amdgcn_global_load_lds(
      (const __attribute__((address_space(1))) void*)g,
      (__attribute__((address_space(3))) void*)l,
      16, 0, 0);
}

__device__ __forceinline__ void cfence() { asm volatile("" ::: "memory"); }

// fp32 -> bf16 canonicalization of hs + weights + biases only (mask handled
// inside the QKV GEMM launch, overlapped with compute).
__global__ void canon_kernel(const float* hs, const float* Wq, const float* bq,
                             const float* Wk, const float* bk, const float* Wv,
                             const float* bv, const float* Wo, const float* bo,
                             __bf16* __restrict__ dst) {
  const float* srcs[9] = {hs, Wq, bq, Wk, bk, Wv, bv, Wo, bo};
  const long starts[10] = {CAN_HS, CAN_WQ, CAN_BQ, CAN_WK, CAN_BK,
                           CAN_WV, CAN_BV, CAN_WO, CAN_BO, CAN_END};
  const long nA = CAN_END / 8;
  for (long c = blockIdx.x * blockDim.x + threadIdx.x; c < nA;
       c += (long)gridDim.x * blockDim.x) {
    const long i = c * 8;
    int seg = 0;
#pragma unroll
    for (int t = 1; t < 9; t++) seg += (i >= starts[t]) ? 1 : 0;
    const float* s = srcs[seg] + (i - starts[seg]);
    bf16x8 v;
#pragma unroll
    for (int e = 0; e < 8; e++) v[e] = (__bf16)s[e];
    *(bf16x8*)(dst + i) = v;
  }
}

// ---------------------------------------------------------------------------
// GEMM: C = A @ W^T + bias (bf16 in).
// MODE 0 (QKV): 128x128 tiles, grid (32, 24 GEMM + 8 mask-prep planes).
// MODE 1 (out-proj): 128x64 tiles, grid (32,16) = 512 blocks.
// r20 K-loop: 4-deep buffers + counted vmcnt (T4). Per iter t:
//   vmcnt(8) [oldest tile's 4 loads done; 8 = 2 future stages in flight]
//   -> s_barrier [tile t visible to all] -> STAGE(t+3) into buf[(t+3)&3]
//   (overwrites buf of tile t-1, whose readers all passed this barrier)
//   -> ds_read frags + MFMA on buf[t&3].
// Epilogue t=30: vmcnt(4); t=31: vmcnt(0). MODE1 (3 loads/stage): 6/3/0.
// launch_bounds (256,2) — r16-verified, no spills.
// ---------------------------------------------------------------------------
template <int MODE, typename OutT>
__global__ __launch_bounds__(256, 2) void gemm_bt(
    const __bf16* __restrict__ A,
    const __bf16* __restrict__ W0, const __bf16* __restrict__ W1,
    const __bf16* __restrict__ W2,
    const __bf16* __restrict__ b0, const __bf16* __restrict__ b1,
    const __bf16* __restrict__ b2,
    OutT* __restrict__ O0, OutT* __restrict__ O1, OutT* __restrict__ O2,
    const float* __restrict__ Mf, __bf16* __restrict__ Mout) {
  constexpr int TN = (MODE == 1) ? 64 : 128;   // N-tile
  constexpr int NACC = TN / 32;                // per-wave 16-col frags
  __shared__ __align__(16) __bf16 sA[4][128 * 32];
  __shared__ __align__(16) __bf16 sB[4][TN * 32];
  const int tid = threadIdx.x;

  if (MODE == 0 && blockIdx.y >= 24) {
    // r19 mask-prep: 256 blocks x 256 threads, 8 grid-stride steps over
    // nT = Bb*32*32*256 = 524288 t-chunks. Coalesced 32B writes; 64-row
    // read gather paid once per batch, overlapped with GEMM compute.
    const long nT = (long)Bb * 32 * 32 * 256;
    const long t0 = ((long)(blockIdx.y - 24) * 32 + blockIdx.x) * 256 + tid;
    for (long tc = t0; tc < nT; tc += 65536) {
      const int t = (int)(tc & 255);
      const long tile = tc >> 8;  // (b*32+qt)*32 + kvt
      const int kvt = (int)(tile & 31);
      const int qt = (int)((tile >> 5) & 31);
      const int b = (int)(tile >> 10);
      const int l31 = t & 31, hi5 = (t >> 5) & 1;
      const int qg = (t >> 6) & 1, kvh = (t >> 7) & 1;
      const int q = qt * 64 + qg * 32 + l31;
      const int kv0 = kvt * 64 + kvh * 32 + hi5 * 4;
      const float* src = Mf + ((long)b * Ss + q) * Ss + kv0;
      bf16x8 o0, o1;
#pragma unroll
      for (int g = 0; g < 4; g++) {
        f32x4 v = *(const f32x4*)(src + g * 8);
#pragma unroll
        for (int r = 0; r < 4; r++) {
          const __bf16 w = (__bf16)(v[r] * LOG2E);
          if (g < 2) o0[g * 4 + r] = w;
          else       o1[(g - 2) * 4 + r] = w;
        }
      }
      __bf16* dstp = Mout + (tile << 12) + t * 16;
      *(bf16x8*)(dstp) = o0;
      *(bf16x8*)(dstp + 8) = o1;
    }
    return;
  }

  const int lane = tid & 63;
  const int wid = tid >> 6;
  const int quad = lane >> 4;
  const int l15 = lane & 15;
  const int mBlock = blockIdx.x * 128;

  const __bf16* W;
  const __bf16* bias;
  OutT* Out;
  int nBlock, which = 0;
  if (MODE == 0) {
    which = blockIdx.y >> 3;  // 0:Q 1:K 2:V
    nBlock = (blockIdx.y & 7) * 128;
    W = which == 0 ? W0 : (which == 1 ? W1 : W2);
    bias = which == 0 ? b0 : (which == 1 ? b1 : b2);
    Out = which == 0 ? O0 : (which == 1 ? O1 : O2);
  } else {
    nBlock = blockIdx.y * TN;
    W = W0;
    bias = b0;
    Out = O0;
  }

  const int waveM = (wid >> 1) * 64;
  const int waveN = (wid & 1) * (TN / 2);

  f32x4 acc[4][NACC] = {};

  const int c1 = wid * 64 + lane;
  const int c2 = c1 + 256;
  const __bf16* Ar1 = A + (mBlock + (c1 >> 2)) * Dd + (c1 & 3) * 8;
  const __bf16* Ar2 = A + (mBlock + (c2 >> 2)) * Dd + (c2 & 3) * 8;
  const __bf16* Wr1 = W + (nBlock + (c1 >> 2)) * Dd + (c1 & 3) * 8;
  const __bf16* Wr2 = W + (nBlock + (c2 >> 2)) * Dd + (c2 & 3) * 8;
  const int d1 = (wid * 64) * 8;
  const int d2 = (wid * 64 + 256) * 8;

  // Per-thread loads per stage: MODE0 = 4, MODE1 = 3 (no Wr2).
#define GSTAGE(BI, K0)                                                        \
  {                                                                           \
    gl_lds16(Ar1 + (K0), sA[BI] + d1);                                        \
    gl_lds16(Ar2 + (K0), sA[BI] + d2);                                        \
    gl_lds16(Wr1 + (K0), sB[BI] + d1);                                        \
    if (MODE == 0) gl_lds16(Wr2 + (K0), sB[BI] + d2);                         \
  }

  // Prologue: tiles 0,1,2 in flight (12 loads MODE0 / 9 MODE1).
  GSTAGE(0, 0);
  GSTAGE(1, 32);
  GSTAGE(2, 64);

#pragma unroll 4
  for (int kt = 0; kt < 32; ++kt) {
    const int bufc = kt & 3;
    cfence();
    if (kt < 30) {
      // Steady state: wait only tile kt's loads; 2 future stages in flight.
      if constexpr (MODE == 0)
        asm volatile("s_waitcnt vmcnt(8)" ::: "memory");
      else
        asm volatile("s_waitcnt vmcnt(6)" ::: "memory");
    } else if (kt == 30) {
      if constexpr (MODE == 0)
        asm volatile("s_waitcnt vmcnt(4)" ::: "memory");
      else
        asm volatile("s_waitcnt vmcnt(3)" ::: "memory");
    } else {
      asm volatile("s_waitcnt vmcnt(0)" ::: "memory");
    }
    cfence();
    __builtin_amdgcn_s_barrier();  // tile kt visible; buf[(kt+3)&3] free
    cfence();
    if (kt < 29) {
      GSTAGE((kt + 3) & 3, (kt + 3) * 32);  // stays in flight across barriers
      cfence();
    }

    bf16x8 aF[4], bF[NACC];
#pragma unroll
    for (int mi = 0; mi < 4; mi++)
      aF[mi] =
          *(const bf16x8*)(sA[bufc] + (waveM + mi * 16 + l15) * 32 + quad * 8);
#pragma unroll
    for (int ni = 0; ni < NACC; ni++)
      bF[ni] =
          *(const bf16x8*)(sB[bufc] + (waveN + ni * 16 + l15) * 32 + quad * 8);
#pragma unroll
    for (int mi = 0; mi < 4; mi++)
#pragma unroll
      for (int ni = 0; ni < NACC; ni++)
        acc[mi][ni] = __builtin_amdgcn_mfma_f32_16x16x32_bf16(
            aF[mi], bF[ni], acc[mi][ni], 0, 0, 0);
  }

  // C/D layout: col = lane&15, row = quad*4 + r.
#pragma unroll
  for (int ni = 0; ni < NACC; ni++) {
    const int ng = nBlock + waveN + ni * 16 + l15;
    const float bv = (float)bias[ng];
#pragma unroll
    for (int mi = 0; mi < 4; mi++) {
      const int mg0 = mBlock + waveM + mi * 16 + quad * 4;
      if (MODE == 0 && which == 2) {
        const int b = mg0 >> 11, s0 = mg0 & 2047;
        const int h = ng >> 6, hd = ng & 63;
        bf16x4 pk;
#pragma unroll
        for (int r = 0; r < 4; r++) pk[r] = (__bf16)(acc[mi][ni][r] + bv);
        *(bf16x4*)((__bf16*)Out + (((b * Hh + h) * HD + hd) * Ss) + s0) = pk;
      } else {
#pragma unroll
        for (int r = 0; r < 4; r++) {
          float v = acc[mi][ni][r] + bv;
          const int m = mg0 + r;
          if (MODE == 0) {
            if (which == 0) v *= SCL2;  // fold softmax scale+log2e into Q
            const int b = m >> 11, s = m & 2047;
            const int h = ng >> 6, hd = ng & 63;
            Out[(((b * Hh + h) * Ss + s) * HD) + hd] = (OutT)v;
          } else {
            Out[m * Dd + ng] = (OutT)v;
          }
        }
      }
    }
  }
}

// ---------------------------------------------------------------------------
// Flash attention (r18, unchanged): 32x32 MFMA, kv-split 2-way, no-max
// softmax. Grid 1024 flat; b-partitioned XCD decode. SINGLE barrier per iter:
//   vmcnt(0) -> barrier (tile i K/V visible + own mask(i) regs loaded)
//   -> STAGE_KV(i+1) + mask(i+1) -> regs (2 coalesced b128 global loads from
//   the pre-permuted fragment-order layout) -> compute(i).
// LDS: kv[2][8KB K | 8KB V] only (32 KB, 4 blocks/CU even packing).
// P-exchange: v_permlane32_swap_b32 (vdst.hi <-> src.lo, r14-verified).
// ---------------------------------------------------------------------------
__global__ __launch_bounds__(256, 4) void attn_fused(
    const __bf16* __restrict__ Qg, const __bf16* __restrict__ Kg,
    const __bf16* __restrict__ Vt, const __bf16* __restrict__ Mbf,
    __bf16* __restrict__ Og) {
  __shared__ __align__(16) union {
    __bf16 kv[2][8192];  // [buffer][K 4096 | V 4096]
    struct {
      float O[2][64][32];  // [qg][hd][q] kv-half-1 partial
      float L[2][32];
    } m;
  } sh;

  const int tid = threadIdx.x;
  const int lane = tid & 63;
  const int wid = tid >> 6;
  const int qg = wid & 1;
  const int kvh = wid >> 1;
  const int l31 = lane & 31;
  const int hi = lane >> 5;

  // b-partitioned XCD-bijective decode (id&7 = XCD under round-robin).
  const int id = blockIdx.x;
  const int j = id >> 3;                   // [0,128)
  const int bh = (id & 7) * 4 + (j >> 5);  // XCD x owns bh {4x..4x+3}
  const int qt = j & 31;                   // q-block index
  const int qb0 = qt * 64;
  const int b = bh >> 4;
  const int h = bh & 15;
  const int qw = qb0 + qg * 32 + l31;      // this lane's q row

  const __bf16* Qp = Qg + (size_t)bh * Ss * HD;
  const __bf16* Kp = Kg + (size_t)bh * Ss * HD;
  const __bf16* Vp = Vt + (size_t)bh * HD * Ss;  // [hd][S]
  // Fragment-order mask: tile (b,qt,kvt) base + tid*16 elems; kvt stride 4096.
  const __bf16* Mt = Mbf + (((long)(b * 32 + qt) * 32) << 12) + tid * 16;

  // Q B-fragments in registers (B[k=hd][n=q]; lane: hd = 16k + 8hi + j).
  bf16x8 qf[4];
#pragma unroll
  for (int k = 0; k < 4; k++)
    qf[k] = *(const bf16x8*)(Qp + (size_t)qw * HD + k * 16 + hi * 8);

  const int cA = tid, cB = 256 + tid;
  // K/V staging (r9-proven): linear LDS dest, source carries the slot
  // swizzle ((row>>1)&3).
#define STAGE_KV(BI, KVS)                                                     \
  {                                                                           \
    const int rwA = (cA & 255) >> 2, rwB = (cB & 255) >> 2;                   \
    const int slA = (cA & 3) ^ ((rwA >> 1) & 3);                              \
    const int slB = (cB & 3) ^ ((rwB >> 1) & 3);                              \
    __bf16* kb = sh.kv[BI];                                                   \
    gl_lds16(Kp + ((KVS) + rwA) * HD + (cA >> 8) * 32 + slA * 8, kb + cA * 8);\
    gl_lds16(Kp + ((KVS) + rwB) * HD + (cB >> 8) * 32 + slB * 8, kb + cB * 8);\
    __bf16* vb = sh.kv[BI] + 4096;                                            \
    gl_lds16(Vp + (size_t)rwA * Ss + (KVS) + (cA >> 8) * 32 + slA * 8,        \
             vb + cA * 8);                                                    \
    gl_lds16(Vp + (size_t)rwB * Ss + (KVS) + (cB >> 8) * 32 + slB * 8,        \
             vb + cB * 8);                                                    \
  }

  f32x16 o[2] = {};  // O^T partials: row=hd (C-layout), col=q
  f32x4 lacc = {0.f, 0.f, 0.f, 0.f};

  const int rsw = (l31 >> 1) & 3;  // K/V read-side slot XOR (row>>1)&3

  // Prologue: tile 0 K/V staged; mask(0) -> registers.
  STAGE_KV(0, 0);
  bf16x8 mc0 = *(const bf16x8*)(Mt);      // g=0,1 (8 values)
  bf16x8 mc1 = *(const bf16x8*)(Mt + 8);  // g=2,3

  for (int it = 0; it < 32; ++it) {
    const int bufc = it & 1;
    cfence();
    asm volatile("s_waitcnt vmcnt(0)" ::: "memory");  // drain stage(it)+mask
    cfence();
    __builtin_amdgcn_s_barrier();  // tile-i K/V visible everywhere
    cfence();
    bf16x8 mn0, mn1;
    if (it < 31) {
      STAGE_KV(bufc ^ 1, (it + 1) * 64);  // K/V prefetch overlaps everything
      cfence();
      mn0 = *(const bf16x8*)(Mt + (it + 1) * 4096);
      mn1 = *(const bf16x8*)(Mt + (it + 1) * 4096 + 8);
      cfence();
    }

    // S^T = K Q^T with C-init = mask (already *log2e; fragment-order regs:
    // mc0 = [g=0,1][r], mc1 = [g=2,3][r]; reg g*4+r <-> kv = 8g+4hi+r).
    f32x16 sacc;
#pragma unroll
    for (int e = 0; e < 8; e++) {
      sacc[e] = (float)mc0[e];
      sacc[8 + e] = (float)mc1[e];
    }
    __builtin_amdgcn_s_setprio(1);
#pragma unroll
    for (int k = 0; k < 4; k++) {
      const int ps = (((k & 1) << 1) | hi) ^ rsw;  // swizzled slot
      bf16x8 kf = *(const bf16x8*)(sh.kv[bufc] +
                                   ((k >> 1) * 64 + kvh * 32 + l31) * 32 +
                                   ps * 8);
      sacc = __builtin_amdgcn_mfma_f32_32x32x16_bf16(kf, qf[k], sacc, 0, 0, 0);
    }
    __builtin_amdgcn_s_setprio(0);

    // p = exp2(s); row-sum into lacc.
    f32x4 sv[4];
#pragma unroll
    for (int g = 0; g < 4; g++)
#pragma unroll
      for (int r = 0; r < 4; r++)
        sv[g][r] = __builtin_amdgcn_exp2f(sacc[g * 4 + r]);
    lacc += (sv[0] + sv[1]) + (sv[2] + sv[3]);

    // P^T B-fragments via v_permlane32_swap_b32 (vdst.hi <-> src.lo):
    //   (a',b') = swap(a = pk[2ks].w, b = pk[2ks+1].w)
    // -> pf[ks] = {a'0, a'1, b'0, b'1} valid for BOTH lane halves.
    union pu { bf16x4 v; uint32_t w[2]; };
    pu pk[4];
#pragma unroll
    for (int g = 0; g < 4; g++)
#pragma unroll
      for (int r = 0; r < 4; r++) pk[g].v[r] = (__bf16)sv[g][r];
    union PF { bf16x8 v; uint32_t u[4]; } pf[2];
#pragma unroll
    for (int ks = 0; ks < 2; ks++) {
      uint32_t a0 = pk[2 * ks].w[0], b0 = pk[2 * ks + 1].w[0];
      uint32_t a1 = pk[2 * ks].w[1], b1 = pk[2 * ks + 1].w[1];
      asm volatile("s_nop 1\n\tv_permlane32_swap_b32 %0, %1"
                   : "+v"(a0), "+v"(b0));
      asm volatile("s_nop 1\n\tv_permlane32_swap_b32 %0, %1"
                   : "+v"(a1), "+v"(b1));
      pf[ks].u[0] = a0;
      pf[ks].u[1] = a1;
      pf[ks].u[2] = b0;
      pf[ks].u[3] = b1;
    }

    // O^T += V^T P^T (contraction over wave's kv 32: 2 ksteps).
    __builtin_amdgcn_s_setprio(1);
#pragma unroll
    for (int k = 0; k < 2; k++)
#pragma unroll
      for (int hb = 0; hb < 2; hb++) {
        const int ps = ((k << 1) | hi) ^ rsw;  // swizzled slot
        bf16x8 vf = *(const bf16x8*)(sh.kv[bufc] + 4096 +
                                     (kvh * 64 + hb * 32 + l31) * 32 +
                                     ps * 8);
        o[hb] = __builtin_amdgcn_mfma_f32_32x32x16_bf16(vf, pf[k].v, o[hb],
                                                        0, 0, 0);
      }
    __builtin_amdgcn_s_setprio(0);

    mc0 = mn0;
    mc1 = mn1;
  }

  float l = lacc[0] + lacc[1] + lacc[2] + lacc[3];
  l += __shfl_xor(l, 32);

  __syncthreads();  // all compute done; union switches to merge arrays
  // Merge kv-halves (plain add — no-max softmax has no rescale factor).
  if (kvh == 1) {
#pragma unroll
    for (int hb = 0; hb < 2; hb++)
#pragma unroll
      for (int r = 0; r < 16; r++) {
        const int hd = hb * 32 + (r & 3) + 8 * (r >> 2) + 4 * hi;
        sh.m.O[qg][hd][l31] = o[hb][r];
      }
    if (hi == 0) sh.m.L[qg][l31] = l;
  }
  __syncthreads();
  if (kvh == 0) {
#pragma unroll
    for (int hb = 0; hb < 2; hb++)
#pragma unroll
      for (int r = 0; r < 16; r++) {
        const int hd = hb * 32 + (r & 3) + 8 * (r >> 2) + 4 * hi;
        o[hb][r] += sh.m.O[qg][hd][l31];
      }
    l += sh.m.L[qg][l31];
    const float inv = 1.0f / l;
    __bf16* Ow = Og + (((size_t)b * Ss + qw) * Hh + h) * HD;
#pragma unroll
    for (int hb = 0; hb < 2; hb++)
#pragma unroll
      for (int g = 0; g < 4; g++) {
        const int hd = hb * 32 + g * 8 + 4 * hi;
        bf16x2 w0, w1;
        w0[0] = (__bf16)(o[hb][g * 4 + 0] * inv);
        w0[1] = (__bf16)(o[hb][g * 4 + 1] * inv);
        w1[0] = (__bf16)(o[hb][g * 4 + 2] * inv);
        w1[1] = (__bf16)(o[hb][g * 4 + 3] * inv);
        *(bf16x2*)(Ow + hd) = w0;
        *(bf16x2*)(Ow + hd + 2) = w1;
      }
  }
}

// ---------------------------------------------------------------------------
extern "C" void kernel_launch(void* const* d_in, const int* in_sizes, int n_in,
                              void* d_out, int out_size, void* d_ws,
                              size_t ws_size, hipStream_t stream) {
  if (ws_size < WS_NEED) return;

  __bf16* ws = (__bf16*)d_ws;
  const __bf16* hsC = ws + CAN_HS;
  const __bf16* WqC = ws + CAN_WQ;
  const __bf16* bqC = ws + CAN_BQ;
  const __bf16* WkC = ws + CAN_WK;
  const __bf16* bkC = ws + CAN_BK;
  const __bf16* WvC = ws + CAN_WV;
  const __bf16* bvC = ws + CAN_BV;
  const __bf16* WoC = ws + CAN_WO;
  const __bf16* boC = ws + CAN_BO;
  __bf16* Q = ws + CAN_END;
  __bf16* K = Q + TSZ;
  __bf16* V = K + TSZ;  // transposed layout [B,H,HD,S]
  __bf16* AW = V + TSZ;
  float* out = (float*)d_out;
  // Fragment-order bf16 mask (pre-scaled by log2e) lives in d_out until
  // out-proj overwrites it: B*S*S bf16 = 16.78MB = B*S*D fp32 exactly.
  __bf16* Mbf = (__bf16*)d_out;

  canon_kernel<<<2048, 256, 0, stream>>>(
      (const float*)d_in[0], (const float*)d_in[2], (const float*)d_in[3],
      (const float*)d_in[4], (const float*)d_in[5], (const float*)d_in[6],
      (const float*)d_in[7], (const float*)d_in[8], (const float*)d_in[9], ws);
  gemm_bt<0, __bf16><<<dim3(32, 32), 256, 0, stream>>>(
      hsC, WqC, WkC, WvC, bqC, bkC, bvC, Q, K, V, (const float*)d_in[1], Mbf);
  attn_fused<<<dim3(1024), 256, 0, stream>>>(Q, K, V, Mbf, AW);
  gemm_bt<1, float><<<dim3(32, 16), 256, 0, stream>>>(
      AW, WoC, WoC, WoC, boC, boC, boC, out, out, out, nullptr, nullptr);
}

// Round 13
// 223.959 us; speedup vs baseline: 1.0335x; 1.0335x over previous
//
#include <hip/hip_runtime.h>
#include <hip/hip_bf16.h>
#include <stdint.h>

// B=2, S=2048, D=1024, H=16, HD=64. Inputs fp32, d_out fp32 (resolved r1-r3).
// canon fp32->bf16 -> QKV GEMM (+ fused mask-prep planes: mask*log2e -> bf16
// PRE-PERMUTED into MFMA-fragment order, stashed in d_out) -> flash attn
// (32x32 MFMA, kv-split 2-way, no-max exp2 softmax, mask read straight to
// registers) -> out-proj GEMM fp32.
// r13: XCD decode + mask bf16 in d_out (89->69us). r14: permlane32_swap
// P-exchange + b-partitioned XCD decode (69->59us). r16: mask prep fused into
// QKV launch. r17 probe: QKV ~42us; ~95us of wall is harness reset
// dispatches. r18/r19: fragment-order mask + register-mask attn.
// r20: counted-vmcnt 4-deep GEMM — REGRESSED (-6us; T4 needs the 8-phase
// regime; 128^2 2-phase GEMM is at its structural ceiling for this shape).
// r21: (a) GEMM reverted to r19's 2-deep __syncthreads form; (b) attn mask
// prefetch TWO tiles deep + vmcnt(2): wait-queue invariant (FIFO)
// [mask(i) 2, KV(i) 8, mask(i+1) 2] -> vmcnt(2) drains mask(i)+KV(i),
// leaves mask(i+1) in flight (2 compute phases to cover ~900cy HBM mask
// latency). Static A/B register slots via manually 2-unrolled body (rule 20);
// issue order pinned by cfence. Tail: mask-issue it<30; vmcnt(0) at it=31.
#define Bb 2
#define Ss 2048
#define Dd 1024
#define Hh 16
#define HD 64

typedef __attribute__((ext_vector_type(8))) __bf16 bf16x8;
typedef __attribute__((ext_vector_type(4))) __bf16 bf16x4;
typedef __attribute__((ext_vector_type(2))) __bf16 bf16x2;
typedef __attribute__((ext_vector_type(4))) float f32x4;
typedef __attribute__((ext_vector_type(16))) float f32x16;

#define LOG2E 1.44269504088896f
#define SCL2 (0.125f * LOG2E)

// ---- workspace layout (bf16 elements) --------------------------------------
#define HS_N   (Bb * Ss * Dd)
#define W_N    (Dd * Dd)
#define B_N    (Dd)
#define MS_N   ((long)Bb * Ss * Ss)
#define CAN_HS 0
#define CAN_WQ (CAN_HS + HS_N)
#define CAN_BQ (CAN_WQ + W_N)
#define CAN_WK (CAN_BQ + B_N)
#define CAN_BK (CAN_WK + W_N)
#define CAN_WV (CAN_BK + B_N)
#define CAN_BV (CAN_WV + W_N)
#define CAN_WO (CAN_BV + B_N)
#define CAN_BO (CAN_WO + W_N)
#define CAN_END (CAN_BO + B_N)
#define TSZ    (Bb * Hh * Ss * HD)
#define WS_ELEMS (CAN_END + 4 * TSZ)
#define WS_NEED ((size_t)WS_ELEMS * 2)

__device__ __forceinline__ void gl_lds16(const __bf16* g, __bf16* l) {
  __builtin_amdgcn_global_load_lds(
      (const __attribute__((address_space(1))) void*)g,
      (__attribute__((address_space(3))) void*)l,
      16, 0, 0);
}

__device__ __forceinline__ void cfence() { asm volatile("" ::: "memory"); }

// fp32 -> bf16 canonicalization of hs + weights + biases only (mask handled
// inside the QKV GEMM launch, overlapped with compute).
__global__ void canon_kernel(const float* hs, const float* Wq, const float* bq,
                             const float* Wk, const float* bk, const float* Wv,
                             const float* bv, const float* Wo, const float* bo,
                             __bf16* __restrict__ dst) {
  const float* srcs[9] = {hs, Wq, bq, Wk, bk, Wv, bv, Wo, bo};
  const long starts[10] = {CAN_HS, CAN_WQ, CAN_BQ, CAN_WK, CAN_BK,
                           CAN_WV, CAN_BV, CAN_WO, CAN_BO, CAN_END};
  const long nA = CAN_END / 8;
  for (long c = blockIdx.x * blockDim.x + threadIdx.x; c < nA;
       c += (long)gridDim.x * blockDim.x) {
    const long i = c * 8;
    int seg = 0;
#pragma unroll
    for (int t = 1; t < 9; t++) seg += (i >= starts[t]) ? 1 : 0;
    const float* s = srcs[seg] + (i - starts[seg]);
    bf16x8 v;
#pragma unroll
    for (int e = 0; e < 8; e++) v[e] = (__bf16)s[e];
    *(bf16x8*)(dst + i) = v;
  }
}

// ---------------------------------------------------------------------------
// GEMM: C = A @ W^T + bias (bf16 in).  (r19-verified 2-deep form)
// MODE 0 (QKV): 128x128 tiles, grid (32, 24 GEMM + 8 mask-prep planes).
// MODE 1 (out-proj): 128x64 tiles, grid (32,16) = 512 blocks.
// launch_bounds (256,2) — r16-verified, no spills.
// ---------------------------------------------------------------------------
template <int MODE, typename OutT>
__global__ __launch_bounds__(256, 2) void gemm_bt(
    const __bf16* __restrict__ A,
    const __bf16* __restrict__ W0, const __bf16* __restrict__ W1,
    const __bf16* __restrict__ W2,
    const __bf16* __restrict__ b0, const __bf16* __restrict__ b1,
    const __bf16* __restrict__ b2,
    OutT* __restrict__ O0, OutT* __restrict__ O1, OutT* __restrict__ O2,
    const float* __restrict__ Mf, __bf16* __restrict__ Mout) {
  constexpr int TN = (MODE == 1) ? 64 : 128;   // N-tile
  constexpr int NACC = TN / 32;                // per-wave 16-col frags
  __shared__ __align__(16) __bf16 sA[2][128 * 32];
  __shared__ __align__(16) __bf16 sB[2][TN * 32];
  const int tid = threadIdx.x;

  if (MODE == 0 && blockIdx.y >= 24) {
    // r19 mask-prep: 256 blocks x 256 threads, 8 grid-stride steps over
    // nT = Bb*32*32*256 = 524288 t-chunks. Coalesced 32B writes; 64-row
    // read gather paid once per batch, overlapped with GEMM compute.
    const long nT = (long)Bb * 32 * 32 * 256;
    const long t0 = ((long)(blockIdx.y - 24) * 32 + blockIdx.x) * 256 + tid;
    for (long tc = t0; tc < nT; tc += 65536) {
      const int t = (int)(tc & 255);
      const long tile = tc >> 8;  // (b*32+qt)*32 + kvt
      const int kvt = (int)(tile & 31);
      const int qt = (int)((tile >> 5) & 31);
      const int b = (int)(tile >> 10);
      const int l31 = t & 31, hi5 = (t >> 5) & 1;
      const int qg = (t >> 6) & 1, kvh = (t >> 7) & 1;
      const int q = qt * 64 + qg * 32 + l31;
      const int kv0 = kvt * 64 + kvh * 32 + hi5 * 4;
      const float* src = Mf + ((long)b * Ss + q) * Ss + kv0;
      bf16x8 o0, o1;
#pragma unroll
      for (int g = 0; g < 4; g++) {
        f32x4 v = *(const f32x4*)(src + g * 8);
#pragma unroll
        for (int r = 0; r < 4; r++) {
          const __bf16 w = (__bf16)(v[r] * LOG2E);
          if (g < 2) o0[g * 4 + r] = w;
          else       o1[(g - 2) * 4 + r] = w;
        }
      }
      __bf16* dstp = Mout + (tile << 12) + t * 16;
      *(bf16x8*)(dstp) = o0;
      *(bf16x8*)(dstp + 8) = o1;
    }
    return;
  }

  const int lane = tid & 63;
  const int wid = tid >> 6;
  const int quad = lane >> 4;
  const int l15 = lane & 15;
  const int mBlock = blockIdx.x * 128;

  const __bf16* W;
  const __bf16* bias;
  OutT* Out;
  int nBlock, which = 0;
  if (MODE == 0) {
    which = blockIdx.y >> 3;  // 0:Q 1:K 2:V
    nBlock = (blockIdx.y & 7) * 128;
    W = which == 0 ? W0 : (which == 1 ? W1 : W2);
    bias = which == 0 ? b0 : (which == 1 ? b1 : b2);
    Out = which == 0 ? O0 : (which == 1 ? O1 : O2);
  } else {
    nBlock = blockIdx.y * TN;
    W = W0;
    bias = b0;
    Out = O0;
  }

  const int waveM = (wid >> 1) * 64;
  const int waveN = (wid & 1) * (TN / 2);

  f32x4 acc[4][NACC] = {};

  const int c1 = wid * 64 + lane;
  const int c2 = c1 + 256;
  const __bf16* Ar1 = A + (mBlock + (c1 >> 2)) * Dd + (c1 & 3) * 8;
  const __bf16* Ar2 = A + (mBlock + (c2 >> 2)) * Dd + (c2 & 3) * 8;
  const __bf16* Wr1 = W + (nBlock + (c1 >> 2)) * Dd + (c1 & 3) * 8;
  const __bf16* Wr2 = W + (nBlock + (c2 >> 2)) * Dd + (c2 & 3) * 8;
  const int d1 = (wid * 64) * 8;
  const int d2 = (wid * 64 + 256) * 8;

#define GSTAGE(BI, K0)                                                        \
  {                                                                           \
    gl_lds16(Ar1 + (K0), sA[BI] + d1);                                        \
    gl_lds16(Ar2 + (K0), sA[BI] + d2);                                        \
    gl_lds16(Wr1 + (K0), sB[BI] + d1);                                        \
    if (MODE == 0) gl_lds16(Wr2 + (K0), sB[BI] + d2);                         \
  }

  GSTAGE(0, 0);  // prologue: tile 0 in flight

#pragma unroll 2
  for (int kt = 0; kt < 32; ++kt) {
    const int bufc = kt & 1;
    __syncthreads();  // implicit s_waitcnt vmcnt(0) = drain stage(kt); barrier
    if (kt < 31) {
      GSTAGE(bufc ^ 1, (kt + 1) * 32);  // overlaps the compute phase
    }

    bf16x8 aF[4], bF[NACC];
#pragma unroll
    for (int mi = 0; mi < 4; mi++)
      aF[mi] =
          *(const bf16x8*)(sA[bufc] + (waveM + mi * 16 + l15) * 32 + quad * 8);
#pragma unroll
    for (int ni = 0; ni < NACC; ni++)
      bF[ni] =
          *(const bf16x8*)(sB[bufc] + (waveN + ni * 16 + l15) * 32 + quad * 8);
#pragma unroll
    for (int mi = 0; mi < 4; mi++)
#pragma unroll
      for (int ni = 0; ni < NACC; ni++)
        acc[mi][ni] = __builtin_amdgcn_mfma_f32_16x16x32_bf16(
            aF[mi], bF[ni], acc[mi][ni], 0, 0, 0);
  }

  // C/D layout: col = lane&15, row = quad*4 + r.
#pragma unroll
  for (int ni = 0; ni < NACC; ni++) {
    const int ng = nBlock + waveN + ni * 16 + l15;
    const float bv = (float)bias[ng];
#pragma unroll
    for (int mi = 0; mi < 4; mi++) {
      const int mg0 = mBlock + waveM + mi * 16 + quad * 4;
      if (MODE == 0 && which == 2) {
        const int b = mg0 >> 11, s0 = mg0 & 2047;
        const int h = ng >> 6, hd = ng & 63;
        bf16x4 pk;
#pragma unroll
        for (int r = 0; r < 4; r++) pk[r] = (__bf16)(acc[mi][ni][r] + bv);
        *(bf16x4*)((__bf16*)Out + (((b * Hh + h) * HD + hd) * Ss) + s0) = pk;
      } else {
#pragma unroll
        for (int r = 0; r < 4; r++) {
          float v = acc[mi][ni][r] + bv;
          const int m = mg0 + r;
          if (MODE == 0) {
            if (which == 0) v *= SCL2;  // fold softmax scale+log2e into Q
            const int b = m >> 11, s = m & 2047;
            const int h = ng >> 6, hd = ng & 63;
            Out[(((b * Hh + h) * Ss + s) * HD) + hd] = (OutT)v;
          } else {
            Out[m * Dd + ng] = (OutT)v;
          }
        }
      }
    }
  }
}

// ---------------------------------------------------------------------------
// Flash attention r21: 32x32 MFMA, kv-split 2-way, no-max softmax.
// Grid 1024 flat; b-partitioned XCD decode.
// r21 schedule: mask prefetch 2 tiles deep. Wait-queue invariant at iter i
// (FIFO): [mask(i) 2, KV(i) 8, mask(i+1) 2] -> vmcnt(2) drains mask(i)+KV(i)
// (all KV of tile i are older than the 2 newest entries), leaves mask(i+1)
// in flight across the barrier. Per iter: vmcnt(2) -> barrier -> cvt mask(i)
// -> sacc -> STAGE_KV(i+1) -> issue mask(i+2) into the just-consumed slot ->
// compute. Static A/B mask slots via manually 2-unrolled body (rule 20);
// issue order pinned by cfence. Tail: mask it<30, KV it<31, vmcnt(0) @31.
// LDS: kv[2][8KB K | 8KB V] (32 KB, 4 blocks/CU).
// P-exchange: v_permlane32_swap_b32 (vdst.hi <-> src.lo, r14-verified).
// ---------------------------------------------------------------------------
__global__ __launch_bounds__(256, 4) void attn_fused(
    const __bf16* __restrict__ Qg, const __bf16* __restrict__ Kg,
    const __bf16* __restrict__ Vt, const __bf16* __restrict__ Mbf,
    __bf16* __restrict__ Og) {
  __shared__ __align__(16) union {
    __bf16 kv[2][8192];  // [buffer][K 4096 | V 4096]
    struct {
      float O[2][64][32];  // [qg][hd][q] kv-half-1 partial
      float L[2][32];
    } m;
  } sh;

  const int tid = threadIdx.x;
  const int lane = tid & 63;
  const int wid = tid >> 6;
  const int qg = wid & 1;
  const int kvh = wid >> 1;
  const int l31 = lane & 31;
  const int hi = lane >> 5;

  // b-partitioned XCD-bijective decode (id&7 = XCD under round-robin).
  const int id = blockIdx.x;
  const int j = id >> 3;                   // [0,128)
  const int bh = (id & 7) * 4 + (j >> 5);  // XCD x owns bh {4x..4x+3}
  const int qt = j & 31;                   // q-block index
  const int qb0 = qt * 64;
  const int b = bh >> 4;
  const int h = bh & 15;
  const int qw = qb0 + qg * 32 + l31;      // this lane's q row

  const __bf16* Qp = Qg + (size_t)bh * Ss * HD;
  const __bf16* Kp = Kg + (size_t)bh * Ss * HD;
  const __bf16* Vp = Vt + (size_t)bh * HD * Ss;  // [hd][S]
  // Fragment-order mask: tile (b,qt,kvt) base + tid*16 elems; kvt stride 4096.
  const __bf16* Mt = Mbf + (((long)(b * 32 + qt) * 32) << 12) + tid * 16;

  // Q B-fragments in registers (B[k=hd][n=q]; lane: hd = 16k + 8hi + j).
  bf16x8 qf[4];
#pragma unroll
  for (int k = 0; k < 4; k++)
    qf[k] = *(const bf16x8*)(Qp + (size_t)qw * HD + k * 16 + hi * 8);

  const int cA = tid, cB = 256 + tid;
  // K/V staging (r9-proven): linear LDS dest, source carries the slot
  // swizzle ((row>>1)&3).
#define STAGE_KV(BI, KVS)                                                     \
  {                                                                           \
    const int rwA = (cA & 255) >> 2, rwB = (cB & 255) >> 2;                   \
    const int slA = (cA & 3) ^ ((rwA >> 1) & 3);                              \
    const int slB = (cB & 3) ^ ((rwB >> 1) & 3);                              \
    __bf16* kb = sh.kv[BI];                                                   \
    gl_lds16(Kp + ((KVS) + rwA) * HD + (cA >> 8) * 32 + slA * 8, kb + cA * 8);\
    gl_lds16(Kp + ((KVS) + rwB) * HD + (cB >> 8) * 32 + slB * 8, kb + cB * 8);\
    __bf16* vb = sh.kv[BI] + 4096;                                            \
    gl_lds16(Vp + (size_t)rwA * Ss + (KVS) + (cA >> 8) * 32 + slA * 8,        \
             vb + cA * 8);                                                    \
    gl_lds16(Vp + (size_t)rwB * Ss + (KVS) + (cB >> 8) * 32 + slB * 8,        \
             vb + cB * 8);                                                    \
  }

  f32x16 o[2] = {};  // O^T partials: row=hd (C-layout), col=q
  f32x4 lacc = {0.f, 0.f, 0.f, 0.f};

  const int rsw = (l31 >> 1) & 3;  // K/V read-side slot XOR (row>>1)&3

  // Prologue — queue must be [mask(0), KV(0), mask(1)] (FIFO order pinned):
  bf16x8 mA0, mA1, mB0, mB1;  // slot A = even tiles, slot B = odd tiles
  mA0 = *(const bf16x8*)(Mt);
  mA1 = *(const bf16x8*)(Mt + 8);
  cfence();
  STAGE_KV(0, 0);
  cfence();
  mB0 = *(const bf16x8*)(Mt + 4096);
  mB1 = *(const bf16x8*)(Mt + 4096 + 8);
  cfence();

  // One iteration; CUR0/CUR1 are the mask slot for tile `it` (it&1 parity),
  // reloaded with mask(it+2) after consumption.
#define ATTN_ITER(IT, CUR0, CUR1)                                             \
  {                                                                           \
    const int it = (IT);                                                      \
    const int bufc = it & 1;                                                  \
    cfence();                                                                 \
    if (it == 31)                                                             \
      asm volatile("s_waitcnt vmcnt(0)" ::: "memory");                        \
    else                                                                      \
      asm volatile("s_waitcnt vmcnt(2)" ::: "memory");                        \
    cfence();                                                                 \
    __builtin_amdgcn_s_barrier();                                             \
    cfence();                                                                 \
    f32x16 sacc;                                                              \
    _Pragma("unroll")                                                         \
    for (int e = 0; e < 8; e++) {                                             \
      sacc[e] = (float)CUR0[e];                                               \
      sacc[8 + e] = (float)CUR1[e];                                           \
    }                                                                         \
    cfence();                                                                 \
    if (it < 31) {                                                            \
      STAGE_KV(bufc ^ 1, (it + 1) * 64);                                      \
      cfence();                                                               \
    }                                                                         \
    if (it < 30) {                                                            \
      CUR0 = *(const bf16x8*)(Mt + (it + 2) * 4096);                          \
      CUR1 = *(const bf16x8*)(Mt + (it + 2) * 4096 + 8);                      \
      cfence();                                                               \
    }                                                                         \
    __builtin_amdgcn_s_setprio(1);                                            \
    _Pragma("unroll")                                                         \
    for (int k = 0; k < 4; k++) {                                             \
      const int ps = (((k & 1) << 1) | hi) ^ rsw;                             \
      bf16x8 kf = *(const bf16x8*)(sh.kv[bufc] +                              \
                                   ((k >> 1) * 64 + kvh * 32 + l31) * 32 +    \
                                   ps * 8);                                   \
      sacc =                                                                  \
          __builtin_amdgcn_mfma_f32_32x32x16_bf16(kf, qf[k], sacc, 0, 0, 0);  \
    }                                                                         \
    __builtin_amdgcn_s_setprio(0);                                            \
    f32x4 sv[4];                                                              \
    _Pragma("unroll")                                                         \
    for (int g = 0; g < 4; g++)                                               \
      _Pragma("unroll")                                                       \
      for (int r = 0; r < 4; r++)                                             \
        sv[g][r] = __builtin_amdgcn_exp2f(sacc[g * 4 + r]);                   \
    lacc += (sv[0] + sv[1]) + (sv[2] + sv[3]);                                \
    union pu { bf16x4 v; uint32_t w[2]; };                                    \
    pu pk[4];                                                                 \
    _Pragma("unroll")                                                         \
    for (int g = 0; g < 4; g++)                                               \
      _Pragma("unroll")                                                       \
      for (int r = 0; r < 4; r++) pk[g].v[r] = (__bf16)sv[g][r];              \
    union PF { bf16x8 v; uint32_t u[4]; } pf[2];                              \
    _Pragma("unroll")                                                         \
    for (int ks = 0; ks < 2; ks++) {                                          \
      uint32_t a0 = pk[2 * ks].w[0], b0 = pk[2 * ks + 1].w[0];                \
      uint32_t a1 = pk[2 * ks].w[1], b1 = pk[2 * ks + 1].w[1];                \
      asm volatile("s_nop 1\n\tv_permlane32_swap_b32 %0, %1"                  \
                   : "+v"(a0), "+v"(b0));                                     \
      asm volatile("s_nop 1\n\tv_permlane32_swap_b32 %0, %1"                  \
                   : "+v"(a1), "+v"(b1));                                     \
      pf[ks].u[0] = a0;                                                       \
      pf[ks].u[1] = a1;                                                       \
      pf[ks].u[2] = b0;                                                       \
      pf[ks].u[3] = b1;                                                       \
    }                                                                         \
    __builtin_amdgcn_s_setprio(1);                                            \
    _Pragma("unroll")                                                         \
    for (int k = 0; k < 2; k++)                                               \
      _Pragma("unroll")                                                       \
      for (int hb = 0; hb < 2; hb++) {                                        \
        const int ps = ((k << 1) | hi) ^ rsw;                                 \
        bf16x8 vf = *(const bf16x8*)(sh.kv[bufc] + 4096 +                     \
                                     (kvh * 64 + hb * 32 + l31) * 32 +        \
                                     ps * 8);                                 \
        o[hb] = __builtin_amdgcn_mfma_f32_32x32x16_bf16(vf, pf[k].v, o[hb],   \
                                                        0, 0, 0);             \
      }                                                                       \
    __builtin_amdgcn_s_setprio(0);                                            \
  }

  for (int it2 = 0; it2 < 16; ++it2) {
    ATTN_ITER(2 * it2, mA0, mA1);      // even tile: slot A
    ATTN_ITER(2 * it2 + 1, mB0, mB1);  // odd tile: slot B
  }
#undef ATTN_ITER

  float l = lacc[0] + lacc[1] + lacc[2] + lacc[3];
  l += __shfl_xor(l, 32);

  __syncthreads();  // all compute done; union switches to merge arrays
  // Merge kv-halves (plain add — no-max softmax has no rescale factor).
  if (kvh == 1) {
#pragma unroll
    for (int hb = 0; hb < 2; hb++)
#pragma unroll
      for (int r = 0; r < 16; r++) {
        const int hd = hb * 32 + (r & 3) + 8 * (r >> 2) + 4 * hi;
        sh.m.O[qg][hd][l31] = o[hb][r];
      }
    if (hi == 0) sh.m.L[qg][l31] = l;
  }
  __syncthreads();
  if (kvh == 0) {
#pragma unroll
    for (int hb = 0; hb < 2; hb++)
#pragma unroll
      for (int r = 0; r < 16; r++) {
        const int hd = hb * 32 + (r & 3) + 8 * (r >> 2) + 4 * hi;
        o[hb][r] += sh.m.O[qg][hd][l31];
      }
    l += sh.m.L[qg][l31];
    const float inv = 1.0f / l;
    __bf16* Ow = Og + (((size_t)b * Ss + qw) * Hh + h) * HD;
#pragma unroll
    for (int hb = 0; hb < 2; hb++)
#pragma unroll
      for (int g = 0; g < 4; g++) {
        const int hd = hb * 32 + g * 8 + 4 * hi;
        bf16x2 w0, w1;
        w0[0] = (__bf16)(o[hb][g * 4 + 0] * inv);
        w0[1] = (__bf16)(o[hb][g * 4 + 1] * inv);
        w1[0] = (__bf16)(o[hb][g * 4 + 2] * inv);
        w1[1] = (__bf16)(o[hb][g * 4 + 3] * inv);
        *(bf16x2*)(Ow + hd) = w0;
        *(bf16x2*)(Ow + hd + 2) = w1;
      }
  }
}

// ---------------------------------------------------------------------------
extern "C" void kernel_launch(void* const* d_in, const int* in_sizes, int n_in,
                              void* d_out, int out_size, void* d_ws,
                              size_t ws_size, hipStream_t stream) {
  if (ws_size < WS_NEED) return;

  __bf16* ws = (__bf16*)d_ws;
  const __bf16* hsC = ws + CAN_HS;
  const __bf16* WqC = ws + CAN_WQ;
  const __bf16* bqC = ws + CAN_BQ;
  const __bf16* WkC = ws + CAN_WK;
  const __bf16* bkC = ws + CAN_BK;
  const __bf16* WvC = ws + CAN_WV;
  const __bf16* bvC = ws + CAN_BV;
  const __bf16* WoC = ws + CAN_WO;
  const __bf16* boC = ws + CAN_BO;
  __bf16* Q = ws + CAN_END;
  __bf16* K = Q + TSZ;
  __bf16* V = K + TSZ;  // transposed layout [B,H,HD,S]
  __bf16* AW = V + TSZ;
  float* out = (float*)d_out;
  // Fragment-order bf16 mask (pre-scaled by log2e) lives in d_out until
  // out-proj overwrites it: B*S*S bf16 = 16.78MB = B*S*D fp32 exactly.
  __bf16* Mbf = (__bf16*)d_out;

  canon_kernel<<<2048, 256, 0, stream>>>(
      (const float*)d_in[0], (const float*)d_in[2], (const float*)d_in[3],
      (const float*)d_in[4], (const float*)d_in[5], (const float*)d_in[6],
      (const float*)d_in[7], (const float*)d_in[8], (const float*)d_in[9], ws);
  gemm_bt<0, __bf16><<<dim3(32, 32), 256, 0, stream>>>(
      hsC, WqC, WkC, WvC, bqC, bkC, bvC, Q, K, V, (const float*)d_in[1], Mbf);
  attn_fused<<<dim3(1024), 256, 0, stream>>>(Q, K, V, Mbf, AW);
  gemm_bt<1, float><<<dim3(32, 16), 256, 0, stream>>>(
      AW, WoC, WoC, WoC, boC, boC, boC, out, out, out, nullptr, nullptr);
}